// Round 5
// baseline (129.008 us; speedup 1.0000x reference)
//
#include <hip/hip_runtime.h>
#include <hip/hip_bf16.h>

typedef __bf16 bf16;
typedef __attribute__((ext_vector_type(8))) __bf16 bf16x8;
typedef __attribute__((ext_vector_type(4))) __bf16 bf16x4;
typedef __attribute__((ext_vector_type(2))) __bf16 bf16x2;
typedef __attribute__((ext_vector_type(4))) float f32x4;

#define IN_F 512
#define OUT_F 128
#define BM 64
#define BK 64
#define NKT (IN_F / BK)
#define CHUNK 128
#define UNR 16

__device__ __forceinline__ void gload_lds16(const void* g, void* l) {
    __builtin_amdgcn_global_load_lds(
        (const __attribute__((address_space(1))) void*)g,
        (__attribute__((address_space(3))) void*)l, 16, 0, 0);
}

// ---- kernel 1: pack W into MFMA-fragment order ----------------------------
// wt_frag layout: [kt(8)][kk(2)][nb(8)] fragments of 64 lanes x bf16x8.
// Lane l of fragment (kt,kk,nb) holds W rows k = kt*64+kk*32+(l>>4)*8 + e,
// col n = nb*16 + (l&15)  -> a wave's B-fragment load is 1KB contiguous.
__global__ __launch_bounds__(256) void wt_convert_kernel(const float* __restrict__ w,
                                                         bf16* __restrict__ wt_frag) {
    int o = blockIdx.x * 256 + threadIdx.x;     // 0..65535
    int e   = o & 7;
    int l   = (o >> 3) & 63;
    int nb  = (o >> 9) & 7;
    int kkt = o >> 12;                          // kt*2+kk, 0..15
    int n = nb * 16 + (l & 15);
    int k = (kkt >> 1) * 64 + (kkt & 1) * 32 + (l >> 4) * 8 + e;
    wt_frag[o] = (bf16)w[k * OUT_F + n];
}

// ---- kernel 2: support = bf16(x @ W), fused out-zeroing --------------------
// 64x128 tile, 4 waves (each 64 rows x 32 cols), 16x16x32 bf16 MFMA.
// A: fp32 staged straight to double-buffered LDS via global_load_lds width-16
//    (16 KB/tile fully in flight), pre-swizzled SOURCE col + swizzled read
//    (rule 21), fp32->bf16 convert after ds_read.
// B: from L2-hot fragment-packed wt (no LDS). B loads issue BEFORE the gloads
//    so waiting on B doesn't drain the prefetch queue.
__global__ __launch_bounds__(256) void gemm_kernel(const float* __restrict__ x,
                                                   const bf16* __restrict__ wt_frag,
                                                   bf16* __restrict__ support,
                                                   float* __restrict__ out,
                                                   int n_nodes) {
    __shared__ float As[2][BM * BK];    // 2 x 16 KB fp32

    const int tid  = threadIdx.x;
    const int lane = tid & 63;
    const int wid  = tid >> 6;          // wave owns cols [wid*32, wid*32+32)
    const int row0 = blockIdx.x * BM;

    // stage A tile kt into As[buf]: lane-linear LDS dest, swizzled global src
    auto stage_tile = [&](int kt, int buf) {
        const int k0 = kt * BK;
        #pragma unroll
        for (int i = 0; i < 4; ++i) {
            int li  = i * 256 + tid;
            int r   = li >> 4;                  // row 0..63
            int c16 = li & 15;                  // 16B unit within row
            int grow = row0 + r;
            if (grow >= n_nodes) grow = n_nodes - 1;   // clamp: row discarded later
            const float* g = x + (size_t)grow * IN_F + k0 + ((c16 ^ (r & 7)) << 2);
            float* l = &As[buf][(size_t)(i * 256 + (tid & ~63)) * 4];
            gload_lds16(g, l);
        }
    };

    stage_tile(0, 0);

    // fused zero-init of this block's output rows (scatter accumulates later)
    {
        float4 z = {0.f, 0.f, 0.f, 0.f};
        const size_t lim = (size_t)n_nodes * OUT_F;
        #pragma unroll
        for (int i = 0; i < 8; ++i) {
            size_t off = (size_t)row0 * OUT_F + (size_t)(i * 256 + tid) * 4;
            if (off < lim)
                *reinterpret_cast<float4*>(out + off) = z;
        }
    }
    __syncthreads();

    f32x4 acc[4][2] = {};

    for (int kt = 0; kt < NKT; ++kt) {
        const int cur = kt & 1;

        // B fragments for this K-step (issue FIRST: newest-vm-op wait for B
        // then only needs vmcnt(#gloads), not a full drain)
        bf16x8 b[2][2];
        #pragma unroll
        for (int kk = 0; kk < 2; ++kk)
            #pragma unroll
            for (int n = 0; n < 2; ++n) {
                int f = (kt * 2 + kk) * 8 + (wid * 2 + n);
                b[kk][n] = *reinterpret_cast<const bf16x8*>(wt_frag + ((size_t)f * 64 + lane) * 8);
            }

        if (kt < NKT - 1) stage_tile(kt + 1, cur ^ 1);   // whole tile in flight

        const float* Af = As[cur];
        #pragma unroll
        for (int kk = 0; kk < 2; ++kk) {
            bf16x8 a[4];
            #pragma unroll
            for (int m = 0; m < 4; ++m) {
                int r  = m * 16 + (lane & 15);
                int u0 = kk * 8 + (lane >> 4) * 2;       // 16B unit within row
                f32x4 f0 = *reinterpret_cast<const f32x4*>(Af + r * 64 + ((u0     ^ (r & 7)) << 2));
                f32x4 f1 = *reinterpret_cast<const f32x4*>(Af + r * 64 + (((u0+1) ^ (r & 7)) << 2));
                a[m][0] = (bf16)f0[0]; a[m][1] = (bf16)f0[1];
                a[m][2] = (bf16)f0[2]; a[m][3] = (bf16)f0[3];
                a[m][4] = (bf16)f1[0]; a[m][5] = (bf16)f1[1];
                a[m][6] = (bf16)f1[2]; a[m][7] = (bf16)f1[3];
            }
            #pragma unroll
            for (int m = 0; m < 4; ++m)
                #pragma unroll
                for (int n = 0; n < 2; ++n)
                    acc[m][n] = __builtin_amdgcn_mfma_f32_16x16x32_bf16(a[m], b[kk][n], acc[m][n], 0, 0, 0);
        }

        if (kt < NKT - 1) __syncthreads();   // drains gloads (structural) + swap
    }

    // ---- epilogue: C/D layout col=lane&15, row=(lane>>4)*4+j -------------
    #pragma unroll
    for (int m = 0; m < 4; ++m) {
        #pragma unroll
        for (int n = 0; n < 2; ++n) {
            #pragma unroll
            for (int j = 0; j < 4; ++j) {
                int gm = row0 + m * 16 + (lane >> 4) * 4 + j;
                int gn = wid * 32 + n * 16 + (lane & 15);
                if (gm < n_nodes)
                    support[(size_t)gm * OUT_F + gn] = (bf16)acc[m][n][j];
            }
        }
    }
}

// ---- kernel 3: segment-sum scatter ---------------------------------------
// 64 threads/block, thread t owns features [2t, 2t+1]. CHUNK sorted edges per
// block. Two-phase unroll: batch UNR independent gathers (all in flight),
// then serial run-accumulate. Interior rows -> plain store, boundary -> atomic.
__global__ __launch_bounds__(64) void scatter_kernel(const int* __restrict__ adj_row,
                                                     const int* __restrict__ adj_col,
                                                     const float* __restrict__ adj_vals,
                                                     const bf16* __restrict__ support,
                                                     float* __restrict__ out,
                                                     int n_edges) {
    __shared__ int   srow[CHUNK];
    __shared__ int   scol[CHUNK];
    __shared__ float sval[CHUNK];

    const int t  = threadIdx.x;          // 0..63
    const int e0 = blockIdx.x * CHUNK;
    const int nE = min(CHUNK, n_edges - e0);

    // stage metadata; pad tail so the unrolled loop needs no bounds checks
    for (int i = t; i < CHUNK; i += 64) {
        if (i < nE) {
            srow[i] = adj_row[e0 + i];
            scol[i] = adj_col[e0 + i];
            sval[i] = adj_vals[e0 + i];
        } else {
            srow[i] = adj_row[e0 + nE - 1];  // extend last run with zero weight
            scol[i] = 0;
            sval[i] = 0.f;
        }
    }
    __syncthreads();

    const int firstRow = srow[0];

    float accx = 0.f, accy = 0.f;
    int   cur = firstRow;

    for (int i0 = 0; i0 < CHUNK; i0 += UNR) {
        // phase 1: UNR independent gathers, issued back-to-back
        float mx[UNR], my[UNR];
        #pragma unroll
        for (int u = 0; u < UNR; ++u) {
            int   c = scol[i0 + u];
            float s = sval[i0 + u];
            bf16x2 v = *reinterpret_cast<const bf16x2*>(support + (size_t)c * OUT_F + t * 2);
            mx[u] = s * (float)v[0];
            my[u] = s * (float)v[1];
        }
        // phase 2: serial run-accumulate (block-uniform branches)
        #pragma unroll
        for (int u = 0; u < UNR; ++u) {
            int r = srow[i0 + u];
            if (r != cur) {
                float* dst = out + (size_t)cur * OUT_F + t * 2;
                if (cur == firstRow) {
                    atomicAdd(dst, accx); atomicAdd(dst + 1, accy);
                } else {
                    dst[0] = accx; dst[1] = accy;
                }
                accx = 0.f; accy = 0.f;
                cur = r;
            }
            accx += mx[u]; accy += my[u];
        }
    }
    // final flush: cur == lastRow (padding guarantees it) -> always atomic
    float* dst = out + (size_t)cur * OUT_F + t * 2;
    atomicAdd(dst, accx); atomicAdd(dst + 1, accy);
}

extern "C" void kernel_launch(void* const* d_in, const int* in_sizes, int n_in,
                              void* d_out, int out_size, void* d_ws, size_t ws_size,
                              hipStream_t stream) {
    const float* x        = (const float*)d_in[0];
    const int*   adj_row  = (const int*)d_in[1];
    const int*   adj_col  = (const int*)d_in[2];
    const float* adj_vals = (const float*)d_in[3];
    const float* weight   = (const float*)d_in[4];
    float*       out      = (float*)d_out;

    const int n_nodes = in_sizes[0] / IN_F;      // 100000
    const int n_edges = in_sizes[1];             // 1600000

    bf16* support = (bf16*)d_ws;                                         // 25.6 MB
    bf16* wt_frag = (bf16*)((char*)d_ws + (size_t)n_nodes * OUT_F * 2);  // 128 KB

    wt_convert_kernel<<<(IN_F * OUT_F) / 256, 256, 0, stream>>>(weight, wt_frag);

    int gemm_blocks = (n_nodes + BM - 1) / BM;   // 1563
    gemm_kernel<<<gemm_blocks, 256, 0, stream>>>(x, wt_frag, support, out, n_nodes);

    int scat_blocks = (n_edges + CHUNK - 1) / CHUNK;  // 12500
    scatter_kernel<<<scat_blocks, 64, 0, stream>>>(adj_row, adj_col, adj_vals,
                                                   support, out, n_edges);
}

// Round 6
// 123.354 us; speedup vs baseline: 1.0458x; 1.0458x over previous
//
#include <hip/hip_runtime.h>
#include <hip/hip_bf16.h>

typedef __bf16 bf16;
typedef __attribute__((ext_vector_type(8))) __bf16 bf16x8;
typedef __attribute__((ext_vector_type(4))) __bf16 bf16x4;
typedef __attribute__((ext_vector_type(2))) __bf16 bf16x2;
typedef __attribute__((ext_vector_type(4))) float f32x4;

#define IN_F 512
#define OUT_F 128
#define BM 64
#define BK 64
#define NKT (IN_F / BK)
#define RPB 32      // rows per scatter block
#define PAGE 512    // edges staged per LDS page
#define UNR 16

// ---- kernel 1: pack W into MFMA-fragment order ----------------------------
__global__ __launch_bounds__(256) void wt_convert_kernel(const float* __restrict__ w,
                                                         bf16* __restrict__ wt_frag) {
    int o = blockIdx.x * 256 + threadIdx.x;     // 0..65535
    int e   = o & 7;
    int l   = (o >> 3) & 63;
    int nb  = (o >> 9) & 7;
    int kkt = o >> 12;                          // kt*2+kk, 0..15
    int n = nb * 16 + (l & 15);
    int k = (kkt >> 1) * 64 + (kkt & 1) * 32 + (l >> 4) * 8 + e;
    wt_frag[o] = (bf16)w[k * OUT_F + n];
}

// ---- kernel 1b: row_ptr[r] = first edge index with adj_row >= r -----------
__global__ __launch_bounds__(256) void row_ptr_kernel(const int* __restrict__ adj_row,
                                                      int* __restrict__ row_ptr,
                                                      int n_edges, int n_nodes) {
    int e = blockIdx.x * 256 + threadIdx.x;
    if (e >= n_edges) return;
    int r1 = adj_row[e];
    int r0 = (e == 0) ? -1 : adj_row[e - 1];
    for (int r = r0 + 1; r <= r1; ++r) row_ptr[r] = e;
    if (e == n_edges - 1)
        for (int r = r1 + 1; r <= n_nodes; ++r) row_ptr[r] = n_edges;
}

// ---- kernel 2: support = bf16(x @ W) ---------------------------------------
// 64x128 tile, 4 waves (each 64 rows x 32 cols), 16x16x32 bf16 MFMA.
// A: reg-staged fp32->bf16 into double-buffered swizzled LDS (16 KB total).
// B: straight from L2-hot fragment-packed wt (no LDS).
__global__ __launch_bounds__(256) void gemm_kernel(const float* __restrict__ x,
                                                   const bf16* __restrict__ wt_frag,
                                                   bf16* __restrict__ support,
                                                   int n_nodes) {
    __shared__ bf16 As[2][BM * BK];     // 2 x 8 KB

    const int tid  = threadIdx.x;
    const int lane = tid & 63;
    const int wid  = tid >> 6;          // wave owns cols [wid*32, wid*32+32)
    const int row0 = blockIdx.x * BM;

    float4 av[4];   // staged A (fp32)

    auto load_tile = [&](int kt) {
        const int k0 = kt * BK;
        #pragma unroll
        for (int i = 0; i < 4; ++i) {           // A: 64 rows x 16 float4
            int li = i * 256 + tid;
            int r = li >> 4, c4 = li & 15;
            int grow = row0 + r;
            float4 v = {0.f, 0.f, 0.f, 0.f};
            if (grow < n_nodes)
                v = *reinterpret_cast<const float4*>(x + (size_t)grow * IN_F + k0 + c4 * 4);
            av[i] = v;
        }
    };

    auto write_tile = [&](int buf) {
        char* Ab = (char*)As[buf];
        #pragma unroll
        for (int i = 0; i < 4; ++i) {
            int li = i * 256 + tid;
            int r = li >> 4, c4 = li & 15;
            bf16x4 b;
            b[0] = (bf16)av[i].x; b[1] = (bf16)av[i].y;
            b[2] = (bf16)av[i].z; b[3] = (bf16)av[i].w;
            *reinterpret_cast<bf16x4*>(Ab + ((r * 128 + c4 * 8) ^ ((r & 7) << 4))) = b;
        }
    };

    load_tile(0);
    write_tile(0);
    __syncthreads();

    f32x4 acc[4][2] = {};

    for (int kt = 0; kt < NKT; ++kt) {
        const int cur = kt & 1;

        // B fragments for this K-step (issue first)
        bf16x8 b[2][2];
        #pragma unroll
        for (int kk = 0; kk < 2; ++kk)
            #pragma unroll
            for (int n = 0; n < 2; ++n) {
                int f = (kt * 2 + kk) * 8 + (wid * 2 + n);
                b[kk][n] = *reinterpret_cast<const bf16x8*>(wt_frag + ((size_t)f * 64 + lane) * 8);
            }

        if (kt < NKT - 1) load_tile(kt + 1);    // in flight across MFMA

        const char* Ab = (const char*)As[cur];
        #pragma unroll
        for (int kk = 0; kk < 2; ++kk) {
            const int kbyte = kk * 64 + (lane >> 4) * 16;
            bf16x8 a[4];
            #pragma unroll
            for (int m = 0; m < 4; ++m) {
                int r = m * 16 + (lane & 15);
                a[m] = *reinterpret_cast<const bf16x8*>(Ab + ((r * 128 + kbyte) ^ ((r & 7) << 4)));
            }
            #pragma unroll
            for (int m = 0; m < 4; ++m)
                #pragma unroll
                for (int n = 0; n < 2; ++n)
                    acc[m][n] = __builtin_amdgcn_mfma_f32_16x16x32_bf16(a[m], b[kk][n], acc[m][n], 0, 0, 0);
        }

        if (kt < NKT - 1) {
            write_tile(cur ^ 1);                // vmcnt wait lands here
            __syncthreads();
        }
    }

    // ---- epilogue: C/D layout col=lane&15, row=(lane>>4)*4+j -------------
    #pragma unroll
    for (int m = 0; m < 4; ++m) {
        #pragma unroll
        for (int n = 0; n < 2; ++n) {
            #pragma unroll
            for (int j = 0; j < 4; ++j) {
                int gm = row0 + m * 16 + (lane >> 4) * 4 + j;
                int gn = wid * 32 + n * 16 + (lane & 15);
                if (gm < n_nodes)
                    support[(size_t)gm * OUT_F + gn] = (bf16)acc[m][n][j];
            }
        }
    }
}

// ---- kernel 3: atomic-free CSR scatter -------------------------------------
// Block owns rows [r0, rEnd) exclusively and the contiguous edge window
// [row_ptr[r0], row_ptr[rEnd]). 64 threads; thread t owns features 2t,2t+1.
// Every owned row is written exactly once (zeros if it has no edges).
__global__ __launch_bounds__(64) void scatter_kernel(const int* __restrict__ adj_row,
                                                     const int* __restrict__ adj_col,
                                                     const float* __restrict__ adj_vals,
                                                     const bf16* __restrict__ support,
                                                     const int* __restrict__ row_ptr,
                                                     float* __restrict__ out,
                                                     int n_nodes) {
    __shared__ int   srow[PAGE];
    __shared__ int   scol[PAGE];
    __shared__ float sval[PAGE];

    const int t    = threadIdx.x;                 // 0..63
    const int r0   = blockIdx.x * RPB;
    const int rEnd = min(r0 + RPB, n_nodes);
    const int eLo  = row_ptr[r0];
    const int eHi  = row_ptr[rEnd];

    float accx = 0.f, accy = 0.f;
    int   cur  = r0;          // row being accumulated; all rows < cur stored

    auto flush_to = [&](int rNew) {   // block-uniform
        if (cur < rEnd) {
            float2 st = {accx, accy};
            *reinterpret_cast<float2*>(out + (size_t)cur * OUT_F + t * 2) = st;
        }
        float2 z = {0.f, 0.f};
        int zhi = rNew < rEnd ? rNew : rEnd;
        for (int r = cur + 1; r < zhi; ++r)
            *reinterpret_cast<float2*>(out + (size_t)r * OUT_F + t * 2) = z;
        accx = 0.f; accy = 0.f;
        cur = rNew;
    };

    for (int base = eLo; base < eHi; base += PAGE) {
        const int nE = min(PAGE, eHi - base);
        __syncthreads();
        for (int i = t; i < nE; i += 64) {
            srow[i] = adj_row[base + i];
            scol[i] = adj_col[base + i];
            sval[i] = adj_vals[base + i];
        }
        __syncthreads();
        if (nE < PAGE) {                      // pad tail: sentinel row, zero val
            for (int i = nE + t; i < PAGE; i += 64) {
                srow[i] = n_nodes;            // sentinel: flushes remaining rows
                scol[i] = 0;
                sval[i] = 0.f;
            }
            __syncthreads();
        }

        for (int i0 = 0; i0 < PAGE; i0 += UNR) {
            if (i0 >= nE) break;              // whole batch is padding
            // phase 1: UNR independent gathers in flight
            float mx[UNR], my[UNR];
            #pragma unroll
            for (int u = 0; u < UNR; ++u) {
                int   c = scol[i0 + u];
                float s = sval[i0 + u];
                bf16x2 v = *reinterpret_cast<const bf16x2*>(support + (size_t)c * OUT_F + t * 2);
                mx[u] = s * (float)v[0];
                my[u] = s * (float)v[1];
            }
            // phase 2: serial run-accumulate (block-uniform branches)
            #pragma unroll
            for (int u = 0; u < UNR; ++u) {
                int r = srow[i0 + u];
                if (r != cur) flush_to(r);
                accx += mx[u]; accy += my[u];
            }
        }
    }
    flush_to(rEnd);   // store last accumulated row + zero-fill trailing rows
}

extern "C" void kernel_launch(void* const* d_in, const int* in_sizes, int n_in,
                              void* d_out, int out_size, void* d_ws, size_t ws_size,
                              hipStream_t stream) {
    const float* x        = (const float*)d_in[0];
    const int*   adj_row  = (const int*)d_in[1];
    const int*   adj_col  = (const int*)d_in[2];
    const float* adj_vals = (const float*)d_in[3];
    const float* weight   = (const float*)d_in[4];
    float*       out      = (float*)d_out;

    const int n_nodes = in_sizes[0] / IN_F;      // 100000
    const int n_edges = in_sizes[1];             // 1600000

    char* ws = (char*)d_ws;
    bf16* support = (bf16*)ws;                                    // 25.6 MB
    bf16* wt_frag = (bf16*)(ws + (size_t)n_nodes * OUT_F * 2);    // 128 KB
    int*  row_ptr = (int*)(ws + (size_t)n_nodes * OUT_F * 2 + IN_F * OUT_F * 2);  // 400 KB

    wt_convert_kernel<<<(IN_F * OUT_F) / 256, 256, 0, stream>>>(weight, wt_frag);

    row_ptr_kernel<<<(n_edges + 255) / 256, 256, 0, stream>>>(adj_row, row_ptr,
                                                              n_edges, n_nodes);

    int gemm_blocks = (n_nodes + BM - 1) / BM;   // 1563
    gemm_kernel<<<gemm_blocks, 256, 0, stream>>>(x, wt_frag, support, n_nodes);

    int scat_blocks = (n_nodes + RPB - 1) / RPB; // 3125
    scatter_kernel<<<scat_blocks, 64, 0, stream>>>(adj_row, adj_col, adj_vals,
                                                   support, row_ptr, out, n_nodes);
}